// Round 1
// baseline (667.914 us; speedup 1.0000x reference)
//
#include <hip/hip_runtime.h>

#define Nn 50000
#define Ee 600000
#define Rr 4
#define NBIN 200704             // 196*1024, padded for int4 scan
#define BN_EPS 1e-5f

typedef __bf16 bfrag  __attribute__((ext_vector_type(8)));
typedef float  f32x4  __attribute__((ext_vector_type(4)));

__device__ __forceinline__ unsigned short f2b(float f) {
    union { float f; unsigned int u; } v; v.f = f;
    return (unsigned short)((v.u + 0x7FFFu + ((v.u >> 16) & 1u)) >> 16);
}
__device__ __forceinline__ float b2f(unsigned short u) {
    union { unsigned int u; float f; } v; v.u = ((unsigned int)u) << 16; return v.f;
}

// ---- prep: xbf (blocks 0..12499) | wt (12500..13075) | hist (13076..15419) ----
__global__ __launch_bounds__(256) void prep_k(
    const float* __restrict__ x, const float* __restrict__ W1,
    const float* __restrict__ W2, const float* __restrict__ Wself,
    const int* __restrict__ ei, const int* __restrict__ et,
    unsigned int* __restrict__ xb, unsigned short* __restrict__ WT,
    int* __restrict__ hist)
{
    int b = blockIdx.x;
    if (b < 12500) {
        int i = b * 256 + threadIdx.x;
        float2 v = ((const float2*)x)[i];
        xb[i] = ((unsigned int)f2b(v.y) << 16) | f2b(v.x);
    } else if (b < 13076) {
        int idx = (b - 12500) * 256 + threadIdx.x;   // < 147456
        int mat = idx >> 14, rem = idx & 16383;
        int n = rem >> 7, k = rem & 127;
        const float* src = (mat < 4) ? (W1 + mat * 16384)
                         : (mat < 8) ? (W2 + (mat - 4) * 16384) : Wself;
        WT[idx] = f2b(src[k * 128 + n]);
    } else {
        int e = (b - 13076) * 256 + threadIdx.x;
        if (e < Ee) atomicAdd(&hist[et[e] * Nn + ei[e]], 1);
    }
}

// ---- exclusive scan over NBIN (block-local) ----
__global__ __launch_bounds__(256) void scan1_k(
    const int* __restrict__ hist, int* __restrict__ offs, int* __restrict__ bsum)
{
    int t = threadIdx.x, b = blockIdx.x;
    int base = b * 1024 + t * 4;
    int4 c = *(const int4*)(hist + base);
    int s = c.x + c.y + c.z + c.w;
    __shared__ int tmp[256];
    tmp[t] = s; __syncthreads();
    for (int off = 1; off < 256; off <<= 1) {
        int v = (t >= off) ? tmp[t - off] : 0;
        __syncthreads(); tmp[t] += v; __syncthreads();
    }
    int excl = tmp[t] - s;
    int4 o; o.x = excl; o.y = excl + c.x; o.z = o.y + c.y; o.w = o.z + c.z;
    *(int4*)(offs + base) = o;
    if (t == 255) bsum[b] = tmp[255];
}
// scan2 folded in: block b sums bsum[0..b-1] itself
__global__ __launch_bounds__(256) void scan3_k(
    int* __restrict__ offs, int* __restrict__ cur, const int* __restrict__ bsum)
{
    int t = threadIdx.x, b = blockIdx.x;
    __shared__ int tmp[256];
    tmp[t] = (t < b) ? bsum[t] : 0;       // b <= 195 < 196 entries
    __syncthreads();
    for (int off = 128; off > 0; off >>= 1) {
        if (t < off) tmp[t] += tmp[t + off];
        __syncthreads();
    }
    int add = tmp[0];
    int base = b * 1024 + t * 4;
    int4 o = *(int4*)(offs + base);
    o.x += add; o.y += add; o.z += add; o.w += add;
    *(int4*)(offs + base) = o;
    *(int4*)(cur + base) = o;
}

// ---- bucket fill: pack (dst & 63) << 16 | src (src < 50000 < 2^16) ----
__global__ __launch_bounds__(256) void fill_k(
    const int* __restrict__ ei, const int* __restrict__ et,
    int* __restrict__ cur, int* __restrict__ ssrc)
{
    int e = blockIdx.x * 256 + threadIdx.x;
    if (e >= Ee) return;
    int dst = ei[e];
    int bin = et[e] * Nn + dst;
    int pos = atomicAdd(&cur[bin], 1);
    ssrc[pos] = ei[Ee + e] | ((dst & 63) << 16);
}

// ---- FUSED: edge-parallel LDS-atomic gather-agg -> @W1_r + b1 -> h1(bf16) + BN stats
//      64-row tiles, 256 threads, grid (782, 4), 2 blocks/CU (LDS 69.6 KB) ----
__global__ __launch_bounds__(256) void gemm1f_k(
    const unsigned int* __restrict__ xb, const int* __restrict__ offs,
    const int* __restrict__ ssrc, const unsigned short* __restrict__ WT,
    const float* __restrict__ b1, unsigned short* __restrict__ h,
    float* __restrict__ gsum, float* __restrict__ gsq)
{
    const int r  = blockIdx.y;
    const int n0 = blockIdx.x * 64;
    const int t  = threadIdx.x;

    // f32 accumulation tile; stride 132 (row term = 4 banks) for the atomic phase.
    __shared__ __attribute__((aligned(16))) float  Asf[64][132];   // 33792 B
    __shared__ __attribute__((aligned(16))) __bf16 Ws[128][136];   // 34816 B
    __shared__ float s_sum[128], s_sq[128];

    if (t < 128) { s_sum[t] = 0.f; s_sq[t] = 0.f; }

    // stage W1_r (bf16, pre-transposed)
    {
        const unsigned short* Wr = WT + r * 16384;
        for (int i = t; i < 2048; i += 256) {
            int n = i >> 4, kc = (i & 15) << 3;
            *(uint4*)&Ws[n][kc] = *(const uint4*)(Wr + n * 128 + kc);
        }
    }

    // init Asf = x[dst] (f32); rows beyond Nn -> 0
    for (int i = t; i < 1024; i += 256) {
        int m = i >> 4, cc = i & 15;
        int gm = n0 + m;
        uint4 u = make_uint4(0, 0, 0, 0);
        if (gm < Nn) u = *(const uint4*)(xb + (size_t)gm * 64 + cc * 4);
        float4 f0 = make_float4(b2f((unsigned short)(u.x & 0xFFFF)), b2f((unsigned short)(u.x >> 16)),
                                b2f((unsigned short)(u.y & 0xFFFF)), b2f((unsigned short)(u.y >> 16)));
        float4 f1 = make_float4(b2f((unsigned short)(u.z & 0xFFFF)), b2f((unsigned short)(u.z >> 16)),
                                b2f((unsigned short)(u.w & 0xFFFF)), b2f((unsigned short)(u.w >> 16)));
        *(float4*)&Asf[m][cc * 8]     = f0;
        *(float4*)&Asf[m][cc * 8 + 4] = f1;
    }

    const int ebeg = offs[r * Nn + n0];
    const int nend = (n0 + 64 < Nn) ? (n0 + 64) : Nn;
    const int ecnt = offs[r * Nn + nend] - ebeg;
    __syncthreads();

    // ---- edge-parallel gather: 16 lanes/edge, 16 edges/round, 2-deep pipeline ----
    {
        const int q  = t & 15;          // feature sub-lane: owns elems {2q,2q+1} per 32-chunk
        const int eg = t >> 4;          // edge slot within round
        const int p0 = eg & 1;          // parity stagger: even/odd groups hit even/odd banks
        const int rounds = (ecnt + 15) >> 4;
        int  eA = eg, eB = eg + 16;
        bool vA = eA < ecnt, vB = eB < ecnt;
        unsigned int pkA = vA ? (unsigned int)ssrc[ebeg + eA] : 0u;
        unsigned int pkB = vB ? (unsigned int)ssrc[ebeg + eB] : 0u;
        uint4 xA = make_uint4(0, 0, 0, 0);
        if (vA) {
            const unsigned int* p = xb + (size_t)(pkA & 0xFFFFu) * 64 + q;
            xA.x = p[0]; xA.y = p[16]; xA.z = p[32]; xA.w = p[48];
        }
        for (int rr = 0; rr < rounds; ++rr) {
            // prefetch packed edge for round rr+2
            int eC = eg + (rr + 2) * 16;
            bool vC = eC < ecnt;
            unsigned int pkC = vC ? (unsigned int)ssrc[ebeg + eC] : 0u;
            // prefetch features for round rr+1 (stride-16 dwords: 64B coalesced per group)
            uint4 xN = make_uint4(0, 0, 0, 0);
            if (vB) {
                const unsigned int* p = xb + (size_t)(pkB & 0xFFFFu) * 64 + q;
                xN.x = p[0]; xN.y = p[16]; xN.z = p[32]; xN.w = p[48];
            }
            // accumulate round rr
            if (vA) {
                int d = (int)(pkA >> 16) & 63;
                float* rowp = &Asf[d][0];
                unsigned int uu[4] = {xA.x, xA.y, xA.z, xA.w};
#pragma unroll
                for (int j = 0; j < 4; ++j) {
                    float v0 = b2f((unsigned short)(uu[j] & 0xFFFF));   // elem j*32 + 2q
                    float v1 = b2f((unsigned short)(uu[j] >> 16));      // elem j*32 + 2q+1
                    float a0 = p0 ? v1 : v0;
                    float a1 = p0 ? v0 : v1;
                    atomicAdd(rowp + j * 32 + 2 * q + p0,       a0);
                    atomicAdd(rowp + j * 32 + 2 * q + (p0 ^ 1), a1);
                }
            }
            pkA = pkB; vA = vB; xA = xN;
            pkB = pkC; vB = vC;
        }
    }
    __syncthreads();

    // ---- MFMA: A-frags straight from f32 tile (convert in regs), B from Ws ----
    const int w = t >> 6, l = t & 63, ln = l & 15, quad = l >> 4;
    f32x4 acc2[8];
#pragma unroll
    for (int c = 0; c < 8; ++c) acc2[c] = (f32x4){0.f, 0.f, 0.f, 0.f};
#pragma unroll
    for (int kk = 0; kk < 4; ++kk) {
        int ks = kk * 32 + quad * 8;
        const float* ap = &Asf[w * 16 + ln][ks];
        float4 a0 = *(const float4*)ap;
        float4 a1 = *(const float4*)(ap + 4);
        union { bfrag b; unsigned short s[8]; } au;
        au.s[0] = f2b(a0.x); au.s[1] = f2b(a0.y); au.s[2] = f2b(a0.z); au.s[3] = f2b(a0.w);
        au.s[4] = f2b(a1.x); au.s[5] = f2b(a1.y); au.s[6] = f2b(a1.z); au.s[7] = f2b(a1.w);
#pragma unroll
        for (int c = 0; c < 8; ++c) {
            bfrag b = *(const bfrag*)&Ws[c * 16 + ln][ks];
            acc2[c] = __builtin_amdgcn_mfma_f32_16x16x32_bf16(au.b, b, acc2[c], 0, 0, 0);
        }
    }
    __syncthreads();

    // ---- epilogue: bias + BN partials; reuse Asf as bf16 staging for h ----
    __bf16 (*Ah)[136] = (__bf16 (*)[136])&Asf[0][0];    // 64*136*2 = 17408 B < 33792
#pragma unroll
    for (int c = 0; c < 8; ++c) {
        int col = c * 16 + ln;
        float bias = b1[r * 128 + col];
        float ps = 0.f, pq = 0.f;
#pragma unroll
        for (int reg = 0; reg < 4; ++reg) {
            int lrow = w * 16 + quad * 4 + reg;
            float v = acc2[c][reg] + bias;
            Ah[lrow][col] = (__bf16)v;
            if (n0 + lrow < Nn) { ps += v; pq += v * v; }
        }
        ps += __shfl_xor(ps, 16); pq += __shfl_xor(pq, 16);
        ps += __shfl_xor(ps, 32); pq += __shfl_xor(pq, 32);
        if (quad == 0) { atomicAdd(&s_sum[col], ps); atomicAdd(&s_sq[col], pq); }
    }
    __syncthreads();

    unsigned short* hr = h + (size_t)r * Nn * 128;
    for (int i = t; i < 1024; i += 256) {
        int m = i >> 4, kc = (i & 15) << 3;
        int gm = n0 + m;
        if (gm < Nn) *(uint4*)(hr + (size_t)gm * 128 + kc) = *(const uint4*)&Ah[m][kc];
    }
    if (t < 128) {
        atomicAdd(&gsum[r * 128 + t], s_sum[t]);
        atomicAdd(&gsq[r * 128 + t],  s_sq[t]);
    }
}

// ---- BN coefs ----
__global__ void finalize_k(
    const float* __restrict__ gsum, const float* __restrict__ gsq,
    const float* __restrict__ gamma, const float* __restrict__ beta,
    float* __restrict__ coefA, float* __restrict__ coefC)
{
    int i = threadIdx.x;   // 512
    float mean = gsum[i] * (1.0f / Nn);
    float var  = gsq[i] * (1.0f / Nn) - mean * mean;
    float a    = gamma[i] * rsqrtf(fmaxf(var, 0.f) + BN_EPS);
    coefA[i] = a;
    coefC[i] = beta[i] - mean * a;
}

// ---- out = x@W_self + sum_r relu(a*h1+c)@W2_r + biases; 128-row tiles, 512 thr ----
__global__ __launch_bounds__(512) void gemm2f_k(
    const unsigned int* __restrict__ xb,
    const unsigned short* __restrict__ h,
    const unsigned short* __restrict__ WT,
    const float* __restrict__ bself, const float* __restrict__ b2,
    const float* __restrict__ coefA, const float* __restrict__ coefC,
    float* __restrict__ out)
{
    const int n0 = blockIdx.x * 128;
    const int t  = threadIdx.x;
    __shared__ __attribute__((aligned(16))) __bf16 As[128][136];
    __shared__ __attribute__((aligned(16))) __bf16 Ws[128][136];

    const int w = t >> 6, l = t & 63, ln = l & 15, quad = l >> 4;
    f32x4 acc2[8];
#pragma unroll
    for (int c = 0; c < 8; ++c) acc2[c] = (f32x4){0.f,0.f,0.f,0.f};

    for (int rr = 0; rr < 5; ++rr) {
        const unsigned short* Wr = WT + (rr < 4 ? (4 + rr) : 8) * 16384;
        for (int i = t; i < 2048; i += 512) {
            int n = i >> 4, kc = (i & 15) << 3;
            *(uint4*)&Ws[n][kc] = *(const uint4*)(Wr + n * 128 + kc);
        }
        if (rr < 4) {
            const unsigned short* hrp = h + (size_t)rr * Nn * 128;
            const float* cA = coefA + rr * 128;
            const float* cC = coefC + rr * 128;
            for (int i = t; i < 2048; i += 512) {
                int m = i >> 4, kc = (i & 15) << 3;
                int gm = n0 + m;
                uint4 hv = make_uint4(0,0,0,0);
                if (gm < Nn) hv = *(const uint4*)(hrp + (size_t)gm * 128 + kc);
                unsigned int hu[4] = {hv.x, hv.y, hv.z, hv.w};
                unsigned int pk[4];
#pragma unroll
                for (int j = 0; j < 4; ++j) {
                    float v0 = fmaxf(cA[kc + 2*j]     * b2f((unsigned short)(hu[j] & 0xFFFF)) + cC[kc + 2*j],     0.f);
                    float v1 = fmaxf(cA[kc + 2*j + 1] * b2f((unsigned short)(hu[j] >> 16))    + cC[kc + 2*j + 1], 0.f);
                    pk[j] = ((unsigned int)f2b(v1) << 16) | f2b(v0);
                }
                *(uint4*)&As[m][kc] = make_uint4(pk[0], pk[1], pk[2], pk[3]);
            }
        } else {
            for (int i = t; i < 2048; i += 512) {
                int m = i >> 4, kc = (i & 15) << 3;
                int gm = n0 + m;
                uint4 v = make_uint4(0, 0, 0, 0);
                if (gm < Nn) v = *(const uint4*)(xb + (size_t)gm * 64 + (kc >> 1));
                *(uint4*)&As[m][kc] = v;
            }
        }
        __syncthreads();
#pragma unroll
        for (int kk = 0; kk < 4; ++kk) {
            int ks = kk * 32 + quad * 8;
            bfrag a = *(const bfrag*)&As[w * 16 + ln][ks];
#pragma unroll
            for (int c = 0; c < 8; ++c) {
                bfrag b = *(const bfrag*)&Ws[c * 16 + ln][ks];
                acc2[c] = __builtin_amdgcn_mfma_f32_16x16x32_bf16(a, b, acc2[c], 0, 0, 0);
            }
        }
        __syncthreads();
    }

    // Epilogue: fp32 transpose through Ws, coalesced stores; 2 passes of 64 rows
    float bias[8];
#pragma unroll
    for (int c = 0; c < 8; ++c) {
        int col = c * 16 + ln;
        bias[c] = bself[col] + b2[col] + b2[128 + col] + b2[256 + col] + b2[384 + col];
    }
    float* fws = (float*)Ws;
    for (int p = 0; p < 2; ++p) {
        if ((w >> 2) == p) {
#pragma unroll
            for (int c = 0; c < 8; ++c) {
                int lrow = (w & 3) * 16 + quad * 4;
                int col  = c * 16 + ln;
#pragma unroll
                for (int reg = 0; reg < 4; ++reg)
                    fws[(lrow + reg) * 132 + col] = acc2[c][reg] + bias[c];
            }
        }
        __syncthreads();
        for (int i = t; i < 2048; i += 512) {
            int m = i >> 5, kc = (i & 31) << 2;
            int gm = n0 + p * 64 + m;
            if (gm < Nn)
                *(float4*)(out + (size_t)gm * 128 + kc) = *(const float4*)&fws[m * 132 + kc];
        }
        __syncthreads();
    }
}

extern "C" void kernel_launch(void* const* d_in, const int* in_sizes, int n_in,
                              void* d_out, int out_size, void* d_ws, size_t ws_size,
                              hipStream_t stream) {
    const float* x     = (const float*)d_in[0];
    const int*   ei    = (const int*)d_in[1];
    const int*   et    = (const int*)d_in[2];
    const float* Wself = (const float*)d_in[3];
    const float* bself = (const float*)d_in[4];
    const float* W1    = (const float*)d_in[5];
    const float* b1    = (const float*)d_in[6];
    const float* gamma = (const float*)d_in[7];
    const float* beta  = (const float*)d_in[8];
    const float* W2    = (const float*)d_in[9];
    const float* b2    = (const float*)d_in[10];
    float* out = (float*)d_out;

    char* ws = (char*)d_ws;
    int*   hist  = (int*)(ws + 0);                      // 802,816
    float* gsum  = (float*)(ws + 802816);               // 2048
    float* gsq   = (float*)(ws + 804864);               // 2048
    float* coefA = (float*)(ws + 806912);               // 2048
    float* coefC = (float*)(ws + 808960);               // 2048
    int*   bsum  = (int*)(ws + 811008);                 // 1024
    int*   offs  = (int*)(ws + 813056);                 // 802,816
    int*   cur   = (int*)(ws + 1615872);                // 802,816
    int*   ssrc  = (int*)(ws + 2418688);                // 2,400,000
    unsigned short* h  = (unsigned short*)(ws + 4818688);   // 51,200,000
    unsigned int*   xb = (unsigned int*)(ws + 56018688);    // 12,800,000
    unsigned short* WT = (unsigned short*)(ws + 68818688);  // 294,912

    (void)hipMemsetAsync(ws, 0, 806912, stream);   // hist + gsum + gsq

    const int EB = (Ee + 255) / 256;                    // 2344
    prep_k <<<12500 + 576 + EB, 256, 0, stream>>>(x, W1, W2, Wself, ei, et, xb, WT, hist);
    scan1_k<<<196, 256, 0, stream>>>(hist, offs, bsum);
    scan3_k<<<196, 256, 0, stream>>>(offs, cur, bsum);
    fill_k <<<EB, 256, 0, stream>>>(ei, et, cur, ssrc);

    dim3 g1((Nn + 63) / 64, Rr);        // (782, 4)
    gemm1f_k<<<g1, 256, 0, stream>>>(xb, offs, ssrc, WT, b1, h, gsum, gsq);
    finalize_k<<<1, 512, 0, stream>>>(gsum, gsq, gamma, beta, coefA, coefC);
    gemm2f_k<<<(Nn + 127) / 128, 512, 0, stream>>>(
        xb, h, WT, bself, b2, coefA, coefC, out);
}

// Round 2
// 268.561 us; speedup vs baseline: 2.4870x; 2.4870x over previous
//
#include <hip/hip_runtime.h>

#define Nn 50000
#define Ee 600000
#define Rr 4
#define NBIN 200704             // 196*1024, padded for int4 scan
#define BN_EPS 1e-5f
#define ECAP 2048               // LDS edge-list cap per block

typedef __bf16 bfrag  __attribute__((ext_vector_type(8)));
typedef float  f32x4  __attribute__((ext_vector_type(4)));

__device__ __forceinline__ unsigned short f2b(float f) {
    union { float f; unsigned int u; } v; v.f = f;
    return (unsigned short)((v.u + 0x7FFFu + ((v.u >> 16) & 1u)) >> 16);
}
__device__ __forceinline__ float b2f(unsigned short u) {
    union { unsigned int u; float f; } v; v.u = ((unsigned int)u) << 16; return v.f;
}

// ---- prep: xbf (blocks 0..12499) | wt (12500..13075) | hist (13076..15419) ----
__global__ __launch_bounds__(256) void prep_k(
    const float* __restrict__ x, const float* __restrict__ W1,
    const float* __restrict__ W2, const float* __restrict__ Wself,
    const int* __restrict__ ei, const int* __restrict__ et,
    unsigned int* __restrict__ xb, unsigned short* __restrict__ WT,
    int* __restrict__ hist)
{
    int b = blockIdx.x;
    if (b < 12500) {
        int i = b * 256 + threadIdx.x;
        float2 v = ((const float2*)x)[i];
        xb[i] = ((unsigned int)f2b(v.y) << 16) | f2b(v.x);
    } else if (b < 13076) {
        int idx = (b - 12500) * 256 + threadIdx.x;   // < 147456
        int mat = idx >> 14, rem = idx & 16383;
        int n = rem >> 7, k = rem & 127;
        const float* src = (mat < 4) ? (W1 + mat * 16384)
                         : (mat < 8) ? (W2 + (mat - 4) * 16384) : Wself;
        WT[idx] = f2b(src[k * 128 + n]);
    } else {
        int e = (b - 13076) * 256 + threadIdx.x;
        if (e < Ee) atomicAdd(&hist[et[e] * Nn + ei[e]], 1);
    }
}

// ---- exclusive scan over NBIN (block-local) ----
__global__ __launch_bounds__(256) void scan1_k(
    const int* __restrict__ hist, int* __restrict__ offs, int* __restrict__ bsum)
{
    int t = threadIdx.x, b = blockIdx.x;
    int base = b * 1024 + t * 4;
    int4 c = *(const int4*)(hist + base);
    int s = c.x + c.y + c.z + c.w;
    __shared__ int tmp[256];
    tmp[t] = s; __syncthreads();
    for (int off = 1; off < 256; off <<= 1) {
        int v = (t >= off) ? tmp[t - off] : 0;
        __syncthreads(); tmp[t] += v; __syncthreads();
    }
    int excl = tmp[t] - s;
    int4 o; o.x = excl; o.y = excl + c.x; o.z = o.y + c.y; o.w = o.z + c.z;
    *(int4*)(offs + base) = o;
    if (t == 255) bsum[b] = tmp[255];
}
// scan2 folded in: block b sums bsum[0..b-1] itself
__global__ __launch_bounds__(256) void scan3_k(
    int* __restrict__ offs, int* __restrict__ cur, const int* __restrict__ bsum)
{
    int t = threadIdx.x, b = blockIdx.x;
    __shared__ int tmp[256];
    tmp[t] = (t < b) ? bsum[t] : 0;       // b <= 195 < 196 entries
    __syncthreads();
    for (int off = 128; off > 0; off >>= 1) {
        if (t < off) tmp[t] += tmp[t + off];
        __syncthreads();
    }
    int add = tmp[0];
    int base = b * 1024 + t * 4;
    int4 o = *(int4*)(offs + base);
    o.x += add; o.y += add; o.z += add; o.w += add;
    *(int4*)(offs + base) = o;
    *(int4*)(cur + base) = o;
}

// ---- bucket fill ----
__global__ __launch_bounds__(256) void fill_k(
    const int* __restrict__ ei, const int* __restrict__ et,
    int* __restrict__ cur, int* __restrict__ ssrc)
{
    int e = blockIdx.x * 256 + threadIdx.x;
    if (e >= Ee) return;
    int bin = et[e] * Nn + ei[e];
    int pos = atomicAdd(&cur[bin], 1);
    ssrc[pos] = ei[Ee + e];
}

#define ACC_QUAD(u0_, u1_, u2_, u3_)                                      \
    do {                                                                  \
        unsigned int uu[16] = {u0_.x,u0_.y,u0_.z,u0_.w, u1_.x,u1_.y,u1_.z,u1_.w, \
                               u2_.x,u2_.y,u2_.z,u2_.w, u3_.x,u3_.y,u3_.z,u3_.w}; \
        _Pragma("unroll")                                                 \
        for (int jj = 0; jj < 16; ++jj) {                                 \
            acc[2*jj]   += b2f((unsigned short)(uu[jj] & 0xFFFF));        \
            acc[2*jj+1] += b2f((unsigned short)(uu[jj] >> 16));           \
        }                                                                 \
    } while (0)

// ---- FUSED: CSR gather-agg (depth-3 rotated pipeline) -> @W1_r + b1 -> h1(bf16) + BN stats
//      128-row tiles, 512 threads, grid (391, 4) ----
__global__ __launch_bounds__(512) void gemm1f_k(
    const unsigned int* __restrict__ xb, const int* __restrict__ offs,
    const int* __restrict__ ssrc, const unsigned short* __restrict__ WT,
    const float* __restrict__ b1, unsigned short* __restrict__ h,
    float* __restrict__ gsum, float* __restrict__ gsq)
{
    const int r  = blockIdx.y;
    const int n0 = blockIdx.x * 128;
    const int t  = threadIdx.x;

    __shared__ __attribute__((aligned(16))) __bf16 As[128][136];
    __shared__ __attribute__((aligned(16))) __bf16 Ws[128][136];
    __shared__ float s_sum[128], s_sq[128];
    __shared__ int s_off[129];
    __shared__ int s_edge[ECAP];

    if (t < 128) { s_sum[t] = 0.f; s_sq[t] = 0.f; }
    const int rows = (Nn - n0 < 128) ? (Nn - n0) : 128;
    if (t <= rows) s_off[t] = offs[r * Nn + n0 + t];
    __syncthreads();

    const int ebeg = s_off[0];
    const int ecnt = s_off[rows] - ebeg;
    const bool inl = (ecnt <= ECAP);
    if (inl) for (int i = t; i < ecnt; i += 512) s_edge[i] = ssrc[ebeg + i];
    {
        const unsigned short* Wr = WT + r * 16384;
        for (int i = t; i < 2048; i += 512) {
            int n = i >> 4, kc = (i & 15) << 3;
            *(uint4*)&Ws[n][kc] = *(const uint4*)(Wr + n * 128 + kc);
        }
    }
    __syncthreads();

    // gather h0 = x[dst] + sum x[src]; 4 thr/row, 16 uints each;
    // depth-3 rotated pipeline: slot loads issue ~2 ACC_QUADs before their use.
    {
        const int row = t >> 2, q = t & 3, gm = n0 + row;
        float acc[32];
#pragma unroll
        for (int j = 0; j < 32; ++j) acc[j] = 0.f;
        if (gm < Nn) {
            const uint4* xr = (const uint4*)(xb + (size_t)gm * 64 + q * 16);
            uint4 u0 = xr[0], u1 = xr[1], u2 = xr[2], u3 = xr[3];
            ACC_QUAD(u0, u1, u2, u3);
            int jb = s_off[row] - ebeg, je = s_off[row + 1] - ebeg;
            if (jb < je) {
                // clamped edge index: lookahead beyond je re-reads je-1 (L1 hit, never accumulated)
#define EIDX(jj) (inl ? s_edge[(jj) < je ? (jj) : (je - 1)] : ssrc[ebeg + ((jj) < je ? (jj) : (je - 1))])
#define EPTR(jj) ((const uint4*)(xb + (size_t)EIDX(jj) * 64 + q * 16))
                const uint4* pA = EPTR(jb);
                const uint4* pB = EPTR(jb + 1);
                const uint4* pC = EPTR(jb + 2);
                uint4 A0 = pA[0], A1 = pA[1], A2 = pA[2], A3 = pA[3];
                uint4 B0 = pB[0], B1 = pB[1], B2 = pB[2], B3 = pB[3];
                uint4 C0 = pC[0], C1 = pC[1], C2 = pC[2], C3 = pC[3];
                for (int j = jb; j < je; j += 3) {
                    ACC_QUAD(A0, A1, A2, A3);
                    { const uint4* p = EPTR(j + 3); A0 = p[0]; A1 = p[1]; A2 = p[2]; A3 = p[3]; }
                    if (j + 1 < je) ACC_QUAD(B0, B1, B2, B3);
                    { const uint4* p = EPTR(j + 4); B0 = p[0]; B1 = p[1]; B2 = p[2]; B3 = p[3]; }
                    if (j + 2 < je) ACC_QUAD(C0, C1, C2, C3);
                    { const uint4* p = EPTR(j + 5); C0 = p[0]; C1 = p[1]; C2 = p[2]; C3 = p[3]; }
                }
#undef EIDX
#undef EPTR
            }
        }
        unsigned int pk[16];
#pragma unroll
        for (int j = 0; j < 16; ++j)
            pk[j] = ((unsigned int)f2b(acc[2*j+1]) << 16) | f2b(acc[2*j]);
        uint4* dst = (uint4*)&As[row][q * 32];
        dst[0] = make_uint4(pk[0],  pk[1],  pk[2],  pk[3]);
        dst[1] = make_uint4(pk[4],  pk[5],  pk[6],  pk[7]);
        dst[2] = make_uint4(pk[8],  pk[9],  pk[10], pk[11]);
        dst[3] = make_uint4(pk[12], pk[13], pk[14], pk[15]);
    }
    __syncthreads();

    const int w = t >> 6, l = t & 63, ln = l & 15, quad = l >> 4;
    f32x4 acc2[8];
#pragma unroll
    for (int c = 0; c < 8; ++c) acc2[c] = (f32x4){0.f,0.f,0.f,0.f};
#pragma unroll
    for (int kk = 0; kk < 4; ++kk) {
        int ks = kk * 32 + quad * 8;
        bfrag a = *(const bfrag*)&As[w * 16 + ln][ks];
#pragma unroll
        for (int c = 0; c < 8; ++c) {
            bfrag b = *(const bfrag*)&Ws[c * 16 + ln][ks];
            acc2[c] = __builtin_amdgcn_mfma_f32_16x16x32_bf16(a, b, acc2[c], 0, 0, 0);
        }
    }
    __syncthreads();

#pragma unroll
    for (int c = 0; c < 8; ++c) {
        int col = c * 16 + ln;
        float bias = b1[r * 128 + col];
        float ps = 0.f, pq = 0.f;
#pragma unroll
        for (int reg = 0; reg < 4; ++reg) {
            int lrow = w * 16 + quad * 4 + reg;
            float v = acc2[c][reg] + bias;
            As[lrow][col] = (__bf16)v;
            if (n0 + lrow < Nn) { ps += v; pq += v * v; }
        }
        ps += __shfl_xor(ps, 16); pq += __shfl_xor(pq, 16);
        ps += __shfl_xor(ps, 32); pq += __shfl_xor(pq, 32);
        if (quad == 0) { atomicAdd(&s_sum[col], ps); atomicAdd(&s_sq[col], pq); }
    }
    __syncthreads();

    unsigned short* hr = h + (size_t)r * Nn * 128;
    for (int i = t; i < 2048; i += 512) {
        int m = i >> 4, kc = (i & 15) << 3;
        int gm = n0 + m;
        if (gm < Nn) *(uint4*)(hr + (size_t)gm * 128 + kc) = *(const uint4*)&As[m][kc];
    }
    if (t < 128) {
        atomicAdd(&gsum[r * 128 + t], s_sum[t]);
        atomicAdd(&gsq[r * 128 + t],  s_sq[t]);
    }
}

// ---- BN coefs ----
__global__ void finalize_k(
    const float* __restrict__ gsum, const float* __restrict__ gsq,
    const float* __restrict__ gamma, const float* __restrict__ beta,
    float* __restrict__ coefA, float* __restrict__ coefC)
{
    int i = threadIdx.x;   // 512
    float mean = gsum[i] * (1.0f / Nn);
    float var  = gsq[i] * (1.0f / Nn) - mean * mean;
    float a    = gamma[i] * rsqrtf(fmaxf(var, 0.f) + BN_EPS);
    coefA[i] = a;
    coefC[i] = beta[i] - mean * a;
}

// ---- out = x@W_self + sum_r relu(a*h1+c)@W2_r + biases; 128-row tiles, 512 thr ----
__global__ __launch_bounds__(512) void gemm2f_k(
    const unsigned int* __restrict__ xb,
    const unsigned short* __restrict__ h,
    const unsigned short* __restrict__ WT,
    const float* __restrict__ bself, const float* __restrict__ b2,
    const float* __restrict__ coefA, const float* __restrict__ coefC,
    float* __restrict__ out)
{
    const int n0 = blockIdx.x * 128;
    const int t  = threadIdx.x;
    __shared__ __attribute__((aligned(16))) __bf16 As[128][136];
    __shared__ __attribute__((aligned(16))) __bf16 Ws[128][136];

    const int w = t >> 6, l = t & 63, ln = l & 15, quad = l >> 4;
    f32x4 acc2[8];
#pragma unroll
    for (int c = 0; c < 8; ++c) acc2[c] = (f32x4){0.f,0.f,0.f,0.f};

    for (int rr = 0; rr < 5; ++rr) {
        const unsigned short* Wr = WT + (rr < 4 ? (4 + rr) : 8) * 16384;
        for (int i = t; i < 2048; i += 512) {
            int n = i >> 4, kc = (i & 15) << 3;
            *(uint4*)&Ws[n][kc] = *(const uint4*)(Wr + n * 128 + kc);
        }
        if (rr < 4) {
            const unsigned short* hrp = h + (size_t)rr * Nn * 128;
            const float* cA = coefA + rr * 128;
            const float* cC = coefC + rr * 128;
            for (int i = t; i < 2048; i += 512) {
                int m = i >> 4, kc = (i & 15) << 3;
                int gm = n0 + m;
                uint4 hv = make_uint4(0,0,0,0);
                if (gm < Nn) hv = *(const uint4*)(hrp + (size_t)gm * 128 + kc);
                unsigned int hu[4] = {hv.x, hv.y, hv.z, hv.w};
                unsigned int pk[4];
#pragma unroll
                for (int j = 0; j < 4; ++j) {
                    float v0 = fmaxf(cA[kc + 2*j]     * b2f((unsigned short)(hu[j] & 0xFFFF)) + cC[kc + 2*j],     0.f);
                    float v1 = fmaxf(cA[kc + 2*j + 1] * b2f((unsigned short)(hu[j] >> 16))    + cC[kc + 2*j + 1], 0.f);
                    pk[j] = ((unsigned int)f2b(v1) << 16) | f2b(v0);
                }
                *(uint4*)&As[m][kc] = make_uint4(pk[0], pk[1], pk[2], pk[3]);
            }
        } else {
            for (int i = t; i < 2048; i += 512) {
                int m = i >> 4, kc = (i & 15) << 3;
                int gm = n0 + m;
                uint4 v = make_uint4(0, 0, 0, 0);
                if (gm < Nn) v = *(const uint4*)(xb + (size_t)gm * 64 + (kc >> 1));
                *(uint4*)&As[m][kc] = v;
            }
        }
        __syncthreads();
#pragma unroll
        for (int kk = 0; kk < 4; ++kk) {
            int ks = kk * 32 + quad * 8;
            bfrag a = *(const bfrag*)&As[w * 16 + ln][ks];
#pragma unroll
            for (int c = 0; c < 8; ++c) {
                bfrag b = *(const bfrag*)&Ws[c * 16 + ln][ks];
                acc2[c] = __builtin_amdgcn_mfma_f32_16x16x32_bf16(a, b, acc2[c], 0, 0, 0);
            }
        }
        __syncthreads();
    }

    // Epilogue: fp32 transpose through Ws, coalesced stores; 2 passes of 64 rows
    float bias[8];
#pragma unroll
    for (int c = 0; c < 8; ++c) {
        int col = c * 16 + ln;
        bias[c] = bself[col] + b2[col] + b2[128 + col] + b2[256 + col] + b2[384 + col];
    }
    float* fws = (float*)Ws;
    for (int p = 0; p < 2; ++p) {
        if ((w >> 2) == p) {
#pragma unroll
            for (int c = 0; c < 8; ++c) {
                int lrow = (w & 3) * 16 + quad * 4;
                int col  = c * 16 + ln;
#pragma unroll
                for (int reg = 0; reg < 4; ++reg)
                    fws[(lrow + reg) * 132 + col] = acc2[c][reg] + bias[c];
            }
        }
        __syncthreads();
        for (int i = t; i < 2048; i += 512) {
            int m = i >> 5, kc = (i & 31) << 2;
            int gm = n0 + p * 64 + m;
            if (gm < Nn)
                *(float4*)(out + (size_t)gm * 128 + kc) = *(const float4*)&fws[m * 132 + kc];
        }
        __syncthreads();
    }
}

extern "C" void kernel_launch(void* const* d_in, const int* in_sizes, int n_in,
                              void* d_out, int out_size, void* d_ws, size_t ws_size,
                              hipStream_t stream) {
    const float* x     = (const float*)d_in[0];
    const int*   ei    = (const int*)d_in[1];
    const int*   et    = (const int*)d_in[2];
    const float* Wself = (const float*)d_in[3];
    const float* bself = (const float*)d_in[4];
    const float* W1    = (const float*)d_in[5];
    const float* b1    = (const float*)d_in[6];
    const float* gamma = (const float*)d_in[7];
    const float* beta  = (const float*)d_in[8];
    const float* W2    = (const float*)d_in[9];
    const float* b2    = (const float*)d_in[10];
    float* out = (float*)d_out;

    char* ws = (char*)d_ws;
    int*   hist  = (int*)(ws + 0);                      // 802,816
    float* gsum  = (float*)(ws + 802816);               // 2048
    float* gsq   = (float*)(ws + 804864);               // 2048
    float* coefA = (float*)(ws + 806912);               // 2048
    float* coefC = (float*)(ws + 808960);               // 2048
    int*   bsum  = (int*)(ws + 811008);                 // 1024
    int*   offs  = (int*)(ws + 813056);                 // 802,816
    int*   cur   = (int*)(ws + 1615872);                // 802,816
    int*   ssrc  = (int*)(ws + 2418688);                // 2,400,000
    unsigned short* h  = (unsigned short*)(ws + 4818688);   // 51,200,000
    unsigned int*   xb = (unsigned int*)(ws + 56018688);    // 12,800,000
    unsigned short* WT = (unsigned short*)(ws + 68818688);  // 294,912

    (void)hipMemsetAsync(ws, 0, 806912, stream);   // hist + gsum + gsq

    const int EB = (Ee + 255) / 256;                    // 2344
    prep_k <<<12500 + 576 + EB, 256, 0, stream>>>(x, W1, W2, Wself, ei, et, xb, WT, hist);
    scan1_k<<<196, 256, 0, stream>>>(hist, offs, bsum);
    scan3_k<<<196, 256, 0, stream>>>(offs, cur, bsum);
    fill_k <<<EB, 256, 0, stream>>>(ei, et, cur, ssrc);

    dim3 g1((Nn + 127) / 128, Rr);      // (391, 4)
    gemm1f_k<<<g1, 512, 0, stream>>>(xb, offs, ssrc, WT, b1, h, gsum, gsq);
    finalize_k<<<1, 512, 0, stream>>>(gsum, gsq, gamma, beta, coefA, coefC);
    gemm2f_k<<<(Nn + 127) / 128, 512, 0, stream>>>(
        xb, h, WT, bself, b2, coefA, coefC, out);
}

// Round 3
// 266.873 us; speedup vs baseline: 2.5027x; 1.0063x over previous
//
#include <hip/hip_runtime.h>

#define Nn 50000
#define Ee 600000
#define Rr 4
#define NBIN 200704             // 196*1024, padded for int4 scan
#define BN_EPS 1e-5f
#define ECAP 2048               // LDS edge-list cap per block

typedef __bf16 bfrag  __attribute__((ext_vector_type(8)));
typedef float  f32x4  __attribute__((ext_vector_type(4)));

__device__ __forceinline__ unsigned short f2b(float f) {
    union { float f; unsigned int u; } v; v.f = f;
    return (unsigned short)((v.u + 0x7FFFu + ((v.u >> 16) & 1u)) >> 16);
}
__device__ __forceinline__ float b2f(unsigned short u) {
    union { unsigned int u; float f; } v; v.u = ((unsigned int)u) << 16; return v.f;
}

// ---- prep: xbf (blocks 0..12499) | wt (12500..13075) | hist (13076..15419) ----
__global__ __launch_bounds__(256) void prep_k(
    const float* __restrict__ x, const float* __restrict__ W1,
    const float* __restrict__ W2, const float* __restrict__ Wself,
    const int* __restrict__ ei, const int* __restrict__ et,
    unsigned int* __restrict__ xb, unsigned short* __restrict__ WT,
    int* __restrict__ hist)
{
    int b = blockIdx.x;
    if (b < 12500) {
        int i = b * 256 + threadIdx.x;
        float2 v = ((const float2*)x)[i];
        xb[i] = ((unsigned int)f2b(v.y) << 16) | f2b(v.x);
    } else if (b < 13076) {
        int idx = (b - 12500) * 256 + threadIdx.x;   // < 147456
        int mat = idx >> 14, rem = idx & 16383;
        int n = rem >> 7, k = rem & 127;
        const float* src = (mat < 4) ? (W1 + mat * 16384)
                         : (mat < 8) ? (W2 + (mat - 4) * 16384) : Wself;
        WT[idx] = f2b(src[k * 128 + n]);
    } else {
        int e = (b - 13076) * 256 + threadIdx.x;
        if (e < Ee) atomicAdd(&hist[et[e] * Nn + ei[e]], 1);
    }
}

// ---- exclusive scan over NBIN (block-local) ----
__global__ __launch_bounds__(256) void scan1_k(
    const int* __restrict__ hist, int* __restrict__ offs, int* __restrict__ bsum)
{
    int t = threadIdx.x, b = blockIdx.x;
    int base = b * 1024 + t * 4;
    int4 c = *(const int4*)(hist + base);
    int s = c.x + c.y + c.z + c.w;
    __shared__ int tmp[256];
    tmp[t] = s; __syncthreads();
    for (int off = 1; off < 256; off <<= 1) {
        int v = (t >= off) ? tmp[t - off] : 0;
        __syncthreads(); tmp[t] += v; __syncthreads();
    }
    int excl = tmp[t] - s;
    int4 o; o.x = excl; o.y = excl + c.x; o.z = o.y + c.y; o.w = o.z + c.z;
    *(int4*)(offs + base) = o;
    if (t == 255) bsum[b] = tmp[255];
}
// scan2 folded in: block b sums bsum[0..b-1] itself
__global__ __launch_bounds__(256) void scan3_k(
    int* __restrict__ offs, int* __restrict__ cur, const int* __restrict__ bsum)
{
    int t = threadIdx.x, b = blockIdx.x;
    __shared__ int tmp[256];
    tmp[t] = (t < b) ? bsum[t] : 0;       // b <= 195 < 196 entries
    __syncthreads();
    for (int off = 128; off > 0; off >>= 1) {
        if (t < off) tmp[t] += tmp[t + off];
        __syncthreads();
    }
    int add = tmp[0];
    int base = b * 1024 + t * 4;
    int4 o = *(int4*)(offs + base);
    o.x += add; o.y += add; o.z += add; o.w += add;
    *(int4*)(offs + base) = o;
    *(int4*)(cur + base) = o;
}

// ---- bucket fill ----
__global__ __launch_bounds__(256) void fill_k(
    const int* __restrict__ ei, const int* __restrict__ et,
    int* __restrict__ cur, int* __restrict__ ssrc)
{
    int e = blockIdx.x * 256 + threadIdx.x;
    if (e >= Ee) return;
    int bin = et[e] * Nn + ei[e];
    int pos = atomicAdd(&cur[bin], 1);
    ssrc[pos] = ei[Ee + e];
}

#define ACC_PAIR(u0_, u1_)                                                \
    do {                                                                  \
        unsigned int uu[8] = {u0_.x, u0_.y, u0_.z, u0_.w,                 \
                              u1_.x, u1_.y, u1_.z, u1_.w};                \
        _Pragma("unroll")                                                 \
        for (int jj = 0; jj < 8; ++jj) {                                  \
            acc[2*jj]   += b2f((unsigned short)(uu[jj] & 0xFFFF));        \
            acc[2*jj+1] += b2f((unsigned short)(uu[jj] >> 16));           \
        }                                                                 \
    } while (0)

// ---- FUSED: CSR gather-agg -> @W1_r + b1 -> h1(bf16) + BN stats
//      128-row tiles, 1024 threads (16 waves), 8 lanes/row, grid (391, 4)
//      __launch_bounds__(1024,8): cap 64 VGPR -> 2 blocks/CU = 32 waves/CU ----
__global__ __launch_bounds__(1024, 8) void gemm1f_k(
    const unsigned int* __restrict__ xb, const int* __restrict__ offs,
    const int* __restrict__ ssrc, const unsigned short* __restrict__ WT,
    const float* __restrict__ b1, unsigned short* __restrict__ h,
    float* __restrict__ gsum, float* __restrict__ gsq)
{
    const int r  = blockIdx.y;
    const int n0 = blockIdx.x * 128;
    const int t  = threadIdx.x;

    __shared__ __attribute__((aligned(16))) __bf16 As[128][136];
    __shared__ __attribute__((aligned(16))) __bf16 Ws[128][136];
    __shared__ float s_sum[128], s_sq[128];
    __shared__ int s_off[129];
    __shared__ int s_edge[ECAP];

    if (t < 128) { s_sum[t] = 0.f; s_sq[t] = 0.f; }
    const int rows = (Nn - n0 < 128) ? (Nn - n0) : 128;
    if (t <= rows) s_off[t] = offs[r * Nn + n0 + t];
    __syncthreads();

    const int ebeg = s_off[0];
    const int ecnt = s_off[rows] - ebeg;
    const bool inl = (ecnt <= ECAP);
    if (inl) for (int i = t; i < ecnt; i += 1024) s_edge[i] = ssrc[ebeg + i];
    {
        const unsigned short* Wr = WT + r * 16384;
        for (int i = t; i < 2048; i += 1024) {
            int n = i >> 4, kc = (i & 15) << 3;
            *(uint4*)&Ws[n][kc] = *(const uint4*)(Wr + n * 128 + kc);
        }
    }
    __syncthreads();

    // gather h0 = x[dst] + sum x[src]; 8 thr/row, 8 uints (16 feats) each;
    // depth-3 rotated pipeline.
    {
        const int row = t >> 3, q = t & 7, gm = n0 + row;
        float acc[16];
#pragma unroll
        for (int j = 0; j < 16; ++j) acc[j] = 0.f;
        if (gm < Nn) {
            const uint4* xr = (const uint4*)(xb + (size_t)gm * 64 + q * 8);
            uint4 u0 = xr[0], u1 = xr[1];
            ACC_PAIR(u0, u1);
            int jb = s_off[row] - ebeg, je = s_off[row + 1] - ebeg;
            if (jb < je) {
                // clamped edge index: lookahead beyond je re-reads je-1 (cache hit, never accumulated)
#define EIDX(jj) (inl ? s_edge[(jj) < je ? (jj) : (je - 1)] : ssrc[ebeg + ((jj) < je ? (jj) : (je - 1))])
#define EPTR(jj) ((const uint4*)(xb + (size_t)EIDX(jj) * 64 + q * 8))
                const uint4* pA = EPTR(jb);
                const uint4* pB = EPTR(jb + 1);
                const uint4* pC = EPTR(jb + 2);
                uint4 A0 = pA[0], A1 = pA[1];
                uint4 B0 = pB[0], B1 = pB[1];
                uint4 C0 = pC[0], C1 = pC[1];
                for (int j = jb; j < je; j += 3) {
                    ACC_PAIR(A0, A1);
                    { const uint4* p = EPTR(j + 3); A0 = p[0]; A1 = p[1]; }
                    if (j + 1 < je) ACC_PAIR(B0, B1);
                    { const uint4* p = EPTR(j + 4); B0 = p[0]; B1 = p[1]; }
                    if (j + 2 < je) ACC_PAIR(C0, C1);
                    { const uint4* p = EPTR(j + 5); C0 = p[0]; C1 = p[1]; }
                }
#undef EIDX
#undef EPTR
            }
        }
        unsigned int pk[8];
#pragma unroll
        for (int j = 0; j < 8; ++j)
            pk[j] = ((unsigned int)f2b(acc[2*j+1]) << 16) | f2b(acc[2*j]);
        uint4* dst = (uint4*)&As[row][q * 16];
        dst[0] = make_uint4(pk[0], pk[1], pk[2], pk[3]);
        dst[1] = make_uint4(pk[4], pk[5], pk[6], pk[7]);
    }
    __syncthreads();

    // 16 waves: wm = row-group (0..7), wc = col-half (0..1); acc2[4] = 4 col-frags
    const int w = t >> 6, l = t & 63, ln = l & 15, quad = l >> 4;
    const int wm = w & 7, wc = w >> 3;
    f32x4 acc2[4];
#pragma unroll
    for (int c = 0; c < 4; ++c) acc2[c] = (f32x4){0.f,0.f,0.f,0.f};
#pragma unroll
    for (int kk = 0; kk < 4; ++kk) {
        int ks = kk * 32 + quad * 8;
        bfrag a = *(const bfrag*)&As[wm * 16 + ln][ks];
#pragma unroll
        for (int c = 0; c < 4; ++c) {
            bfrag b = *(const bfrag*)&Ws[wc * 64 + c * 16 + ln][ks];
            acc2[c] = __builtin_amdgcn_mfma_f32_16x16x32_bf16(a, b, acc2[c], 0, 0, 0);
        }
    }
    __syncthreads();

#pragma unroll
    for (int c = 0; c < 4; ++c) {
        int col = wc * 64 + c * 16 + ln;
        float bias = b1[r * 128 + col];
        float ps = 0.f, pq = 0.f;
#pragma unroll
        for (int reg = 0; reg < 4; ++reg) {
            int lrow = wm * 16 + quad * 4 + reg;
            float v = acc2[c][reg] + bias;
            As[lrow][col] = (__bf16)v;
            if (n0 + lrow < Nn) { ps += v; pq += v * v; }
        }
        ps += __shfl_xor(ps, 16); pq += __shfl_xor(pq, 16);
        ps += __shfl_xor(ps, 32); pq += __shfl_xor(pq, 32);
        if (quad == 0) { atomicAdd(&s_sum[col], ps); atomicAdd(&s_sq[col], pq); }
    }
    __syncthreads();

    unsigned short* hr = h + (size_t)r * Nn * 128;
    for (int i = t; i < 2048; i += 1024) {
        int m = i >> 4, kc = (i & 15) << 3;
        int gm = n0 + m;
        if (gm < Nn) *(uint4*)(hr + (size_t)gm * 128 + kc) = *(const uint4*)&As[m][kc];
    }
    if (t < 128) {
        atomicAdd(&gsum[r * 128 + t], s_sum[t]);
        atomicAdd(&gsq[r * 128 + t],  s_sq[t]);
    }
}

// ---- BN coefs ----
__global__ void finalize_k(
    const float* __restrict__ gsum, const float* __restrict__ gsq,
    const float* __restrict__ gamma, const float* __restrict__ beta,
    float* __restrict__ coefA, float* __restrict__ coefC)
{
    int i = threadIdx.x;   // 512
    float mean = gsum[i] * (1.0f / Nn);
    float var  = gsq[i] * (1.0f / Nn) - mean * mean;
    float a    = gamma[i] * rsqrtf(fmaxf(var, 0.f) + BN_EPS);
    coefA[i] = a;
    coefC[i] = beta[i] - mean * a;
}

// ---- out = x@W_self + sum_r relu(a*h1+c)@W2_r + biases; 128-row tiles, 512 thr ----
__global__ __launch_bounds__(512) void gemm2f_k(
    const unsigned int* __restrict__ xb,
    const unsigned short* __restrict__ h,
    const unsigned short* __restrict__ WT,
    const float* __restrict__ bself, const float* __restrict__ b2,
    const float* __restrict__ coefA, const float* __restrict__ coefC,
    float* __restrict__ out)
{
    const int n0 = blockIdx.x * 128;
    const int t  = threadIdx.x;
    __shared__ __attribute__((aligned(16))) __bf16 As[128][136];
    __shared__ __attribute__((aligned(16))) __bf16 Ws[128][136];

    const int w = t >> 6, l = t & 63, ln = l & 15, quad = l >> 4;
    f32x4 acc2[8];
#pragma unroll
    for (int c = 0; c < 8; ++c) acc2[c] = (f32x4){0.f,0.f,0.f,0.f};

    for (int rr = 0; rr < 5; ++rr) {
        const unsigned short* Wr = WT + (rr < 4 ? (4 + rr) : 8) * 16384;
        for (int i = t; i < 2048; i += 512) {
            int n = i >> 4, kc = (i & 15) << 3;
            *(uint4*)&Ws[n][kc] = *(const uint4*)(Wr + n * 128 + kc);
        }
        if (rr < 4) {
            const unsigned short* hrp = h + (size_t)rr * Nn * 128;
            const float* cA = coefA + rr * 128;
            const float* cC = coefC + rr * 128;
            for (int i = t; i < 2048; i += 512) {
                int m = i >> 4, kc = (i & 15) << 3;
                int gm = n0 + m;
                uint4 hv = make_uint4(0,0,0,0);
                if (gm < Nn) hv = *(const uint4*)(hrp + (size_t)gm * 128 + kc);
                unsigned int hu[4] = {hv.x, hv.y, hv.z, hv.w};
                unsigned int pk[4];
#pragma unroll
                for (int j = 0; j < 4; ++j) {
                    float v0 = fmaxf(cA[kc + 2*j]     * b2f((unsigned short)(hu[j] & 0xFFFF)) + cC[kc + 2*j],     0.f);
                    float v1 = fmaxf(cA[kc + 2*j + 1] * b2f((unsigned short)(hu[j] >> 16))    + cC[kc + 2*j + 1], 0.f);
                    pk[j] = ((unsigned int)f2b(v1) << 16) | f2b(v0);
                }
                *(uint4*)&As[m][kc] = make_uint4(pk[0], pk[1], pk[2], pk[3]);
            }
        } else {
            for (int i = t; i < 2048; i += 512) {
                int m = i >> 4, kc = (i & 15) << 3;
                int gm = n0 + m;
                uint4 v = make_uint4(0, 0, 0, 0);
                if (gm < Nn) v = *(const uint4*)(xb + (size_t)gm * 64 + (kc >> 1));
                *(uint4*)&As[m][kc] = v;
            }
        }
        __syncthreads();
#pragma unroll
        for (int kk = 0; kk < 4; ++kk) {
            int ks = kk * 32 + quad * 8;
            bfrag a = *(const bfrag*)&As[w * 16 + ln][ks];
#pragma unroll
            for (int c = 0; c < 8; ++c) {
                bfrag b = *(const bfrag*)&Ws[c * 16 + ln][ks];
                acc2[c] = __builtin_amdgcn_mfma_f32_16x16x32_bf16(a, b, acc2[c], 0, 0, 0);
            }
        }
        __syncthreads();
    }

    // Epilogue: fp32 transpose through Ws, coalesced stores; 2 passes of 64 rows
    float bias[8];
#pragma unroll
    for (int c = 0; c < 8; ++c) {
        int col = c * 16 + ln;
        bias[c] = bself[col] + b2[col] + b2[128 + col] + b2[256 + col] + b2[384 + col];
    }
    float* fws = (float*)Ws;
    for (int p = 0; p < 2; ++p) {
        if ((w >> 2) == p) {
#pragma unroll
            for (int c = 0; c < 8; ++c) {
                int lrow = (w & 3) * 16 + quad * 4;
                int col  = c * 16 + ln;
#pragma unroll
                for (int reg = 0; reg < 4; ++reg)
                    fws[(lrow + reg) * 132 + col] = acc2[c][reg] + bias[c];
            }
        }
        __syncthreads();
        for (int i = t; i < 2048; i += 512) {
            int m = i >> 5, kc = (i & 31) << 2;
            int gm = n0 + p * 64 + m;
            if (gm < Nn)
                *(float4*)(out + (size_t)gm * 128 + kc) = *(const float4*)&fws[m * 132 + kc];
        }
        __syncthreads();
    }
}

extern "C" void kernel_launch(void* const* d_in, const int* in_sizes, int n_in,
                              void* d_out, int out_size, void* d_ws, size_t ws_size,
                              hipStream_t stream) {
    const float* x     = (const float*)d_in[0];
    const int*   ei    = (const int*)d_in[1];
    const int*   et    = (const int*)d_in[2];
    const float* Wself = (const float*)d_in[3];
    const float* bself = (const float*)d_in[4];
    const float* W1    = (const float*)d_in[5];
    const float* b1    = (const float*)d_in[6];
    const float* gamma = (const float*)d_in[7];
    const float* beta  = (const float*)d_in[8];
    const float* W2    = (const float*)d_in[9];
    const float* b2    = (const float*)d_in[10];
    float* out = (float*)d_out;

    char* ws = (char*)d_ws;
    int*   hist  = (int*)(ws + 0);                      // 802,816
    float* gsum  = (float*)(ws + 802816);               // 2048
    float* gsq   = (float*)(ws + 804864);               // 2048
    float* coefA = (float*)(ws + 806912);               // 2048
    float* coefC = (float*)(ws + 808960);               // 2048
    int*   bsum  = (int*)(ws + 811008);                 // 1024
    int*   offs  = (int*)(ws + 813056);                 // 802,816
    int*   cur   = (int*)(ws + 1615872);                // 802,816
    int*   ssrc  = (int*)(ws + 2418688);                // 2,400,000
    unsigned short* h  = (unsigned short*)(ws + 4818688);   // 51,200,000
    unsigned int*   xb = (unsigned int*)(ws + 56018688);    // 12,800,000
    unsigned short* WT = (unsigned short*)(ws + 68818688);  // 294,912

    (void)hipMemsetAsync(ws, 0, 806912, stream);   // hist + gsum + gsq

    const int EB = (Ee + 255) / 256;                    // 2344
    prep_k <<<12500 + 576 + EB, 256, 0, stream>>>(x, W1, W2, Wself, ei, et, xb, WT, hist);
    scan1_k<<<196, 256, 0, stream>>>(hist, offs, bsum);
    scan3_k<<<196, 256, 0, stream>>>(offs, cur, bsum);
    fill_k <<<EB, 256, 0, stream>>>(ei, et, cur, ssrc);

    dim3 g1((Nn + 127) / 128, Rr);      // (391, 4)
    gemm1f_k<<<g1, 1024, 0, stream>>>(xb, offs, ssrc, WT, b1, h, gsum, gsq);
    finalize_k<<<1, 512, 0, stream>>>(gsum, gsq, gamma, beta, coefA, coefC);
    gemm2f_k<<<(Nn + 127) / 128, 512, 0, stream>>>(
        xb, h, WT, bself, b2, coefA, coefC, out);
}

// Round 4
// 250.644 us; speedup vs baseline: 2.6648x; 1.0647x over previous
//
#include <hip/hip_runtime.h>

#define Nn 50000
#define Ee 600000
#define Rr 4
#define BN_EPS 1e-5f
#define SUBCAP 80               // entries per (bucket, sub) run; mean 48, +4.6 sigma
#define ECAP 896                // 8*SUBCAP + overflow headroom
#define OVFCAP 255

typedef __bf16 bfrag  __attribute__((ext_vector_type(8)));
typedef float  f32x4  __attribute__((ext_vector_type(4)));

__device__ __forceinline__ unsigned short f2b(float f) {
    union { float f; unsigned int u; } v; v.f = f;
    return (unsigned short)((v.u + 0x7FFFu + ((v.u >> 16) & 1u)) >> 16);
}
__device__ __forceinline__ float b2f(unsigned short u) {
    union { unsigned int u; float f; } v; v.u = ((unsigned int)u) << 16; return v.f;
}

// ---- prep: xbf (blocks 0..12499) | WT transpose (12500..13075) ----
__global__ __launch_bounds__(256) void prep_k(
    const float* __restrict__ x, const float* __restrict__ W1,
    const float* __restrict__ W2, const float* __restrict__ Wself,
    unsigned int* __restrict__ xb, unsigned short* __restrict__ WT)
{
    int b = blockIdx.x;
    if (b < 12500) {
        int i = b * 256 + threadIdx.x;
        float2 v = ((const float2*)x)[i];
        xb[i] = ((unsigned int)f2b(v.y) << 16) | f2b(v.x);
    } else {
        int idx = (b - 12500) * 256 + threadIdx.x;   // < 147456
        int mat = idx >> 14, rem = idx & 16383;
        int n = rem >> 7, k = rem & 127;
        const float* src = (mat < 4) ? (W1 + mat * 16384)
                         : (mat < 8) ? (W2 + (mat - 4) * 16384) : Wself;
        WT[idx] = f2b(src[k * 128 + n]);
    }
}

// ---- direct sub-bucket scatter: bucket = (dst>>7)*4 + rel, sub = blockIdx%8 (XCD proxy)
//      scnt: one 64B line per sub-counter; bkt runs contiguous; overflow -> ovf list ----
__global__ __launch_bounds__(256) void fill2_k(
    const int* __restrict__ ei, const int* __restrict__ et,
    int* __restrict__ scnt, int* __restrict__ bkt, int* __restrict__ ovf)
{
    int e = blockIdx.x * 256 + threadIdx.x;
    if (e >= Ee) return;
    int dst = ei[e], rel = et[e], src = ei[Ee + e];
    int bucket = ((dst >> 7) << 2) | rel;
    int sc = (bucket << 3) | (blockIdx.x & 7);
    int pos = atomicAdd(&scnt[sc * 16], 1);
    int pk = ((dst & 127) << 16) | src;
    if (pos < SUBCAP) {
        bkt[sc * SUBCAP + pos] = pk;
    } else {
        int op = atomicAdd(&ovf[0], 1);
        if (op < OVFCAP) { ovf[1 + op * 2] = bucket; ovf[2 + op * 2] = pk; }
    }
}

#define ACC_QUAD(u0_, u1_, u2_, u3_)                                      \
    do {                                                                  \
        unsigned int uu[16] = {u0_.x,u0_.y,u0_.z,u0_.w, u1_.x,u1_.y,u1_.z,u1_.w, \
                               u2_.x,u2_.y,u2_.z,u2_.w, u3_.x,u3_.y,u3_.z,u3_.w}; \
        _Pragma("unroll")                                                 \
        for (int jj = 0; jj < 16; ++jj) {                                 \
            acc[2*jj]   += b2f((unsigned short)(uu[jj] & 0xFFFF));        \
            acc[2*jj+1] += b2f((unsigned short)(uu[jj] >> 16));           \
        }                                                                 \
    } while (0)

// ---- FUSED: LDS row-CSR build -> CSR gather-agg -> @W1_r + b1 -> h1(bf16) + BN stats
//      128-row tiles, 512 threads, grid (391, 4) ----
__global__ __launch_bounds__(512) void gemm1f_k(
    const unsigned int* __restrict__ xb, const int* __restrict__ scnt,
    const int* __restrict__ bkt, const int* __restrict__ ovf,
    const unsigned short* __restrict__ WT,
    const float* __restrict__ b1, unsigned short* __restrict__ h,
    float* __restrict__ gsum, float* __restrict__ gsq)
{
    const int r  = blockIdx.y;
    const int n0 = blockIdx.x * 128;
    const int t  = threadIdx.x;

    __shared__ __attribute__((aligned(16))) __bf16 As[128][136];
    __shared__ __attribute__((aligned(16))) __bf16 Ws[128][136];
    __shared__ float s_sum[128], s_sq[128];
    __shared__ int s_off[129];      // row counts -> exclusive offsets
    __shared__ int s_rcur[128];
    __shared__ int s_sub[9];
    __shared__ int s_tot;
    __shared__ int s_raw[ECAP];
    __shared__ int s_edge[ECAP];

    if (t < 128) { s_sum[t] = 0.f; s_sq[t] = 0.f; }
    if (t < 129) s_off[t] = 0;

    const int bucket = (blockIdx.x << 2) | r;
    if (t < 8) {
        int c = scnt[((bucket << 3) | t) * 16];
        s_sub[t + 1] = (c < SUBCAP) ? c : SUBCAP;
        if (t == 0) s_sub[0] = 0;
    }
    {   // stage W1_r (bf16, pre-transposed)
        const unsigned short* Wr = WT + r * 16384;
        for (int i = t; i < 2048; i += 512) {
            int n = i >> 4, kc = (i & 15) << 3;
            *(uint4*)&Ws[n][kc] = *(const uint4*)(Wr + n * 128 + kc);
        }
    }
    __syncthreads();

    if (t == 0) {   // prefix over sub-runs
        int a = 0;
#pragma unroll
        for (int s = 0; s < 8; ++s) { int c = s_sub[s + 1]; s_sub[s] = a; a += c; }
        s_sub[8] = a;
    }
    __syncthreads();

    // stage the 8 contiguous runs into s_raw
#pragma unroll
    for (int s = 0; s < 8; ++s) {
        int base = s_sub[s], c = s_sub[s + 1] - base;
        const int* bp = bkt + (((bucket << 3) | s) * SUBCAP);
        for (int i = t; i < c; i += 512) s_raw[base + i] = bp[i];
    }
    if (t == 0) {   // append any overflow entries for this bucket (normally zero)
        int tot = s_sub[8];
        int on = ovf[0]; if (on > OVFCAP) on = OVFCAP;
        for (int i = 0; i < on; ++i)
            if (ovf[1 + i * 2] == bucket && tot < ECAP) s_raw[tot++] = ovf[2 + i * 2];
        s_tot = tot;
    }
    __syncthreads();

    const int tot = s_tot;
    // row histogram
    for (int i = t; i < tot; i += 512) atomicAdd(&s_off[1 + ((s_raw[i] >> 16) & 127)], 1);
    __syncthreads();
    // inclusive scan over s_off[0..128] -> exclusive row offsets
    for (int off = 1; off < 129; off <<= 1) {
        int v = 0;
        if (t < 129 && t >= off) v = s_off[t - off];
        __syncthreads();
        if (t < 129) s_off[t] += v;
        __syncthreads();
    }
    if (t < 128) s_rcur[t] = s_off[t];
    __syncthreads();
    // scatter srcs into row-sorted order
    for (int i = t; i < tot; i += 512) {
        int pk = s_raw[i];
        int p = atomicAdd(&s_rcur[(pk >> 16) & 127], 1);
        s_edge[p] = pk & 0xFFFF;
    }
    __syncthreads();

    // gather h0 = x[dst] + sum x[src]; 4 thr/row, 16 uints each; depth-3 rotated pipeline
    {
        const int row = t >> 2, q = t & 3, gm = n0 + row;
        float acc[32];
#pragma unroll
        for (int j = 0; j < 32; ++j) acc[j] = 0.f;
        if (gm < Nn) {
            const uint4* xr = (const uint4*)(xb + (size_t)gm * 64 + q * 16);
            uint4 u0 = xr[0], u1 = xr[1], u2 = xr[2], u3 = xr[3];
            ACC_QUAD(u0, u1, u2, u3);
            int jb = s_off[row], je = s_off[row + 1];
            if (jb < je) {
#define EIDX(jj) (s_edge[(jj) < je ? (jj) : (je - 1)])
#define EPTR(jj) ((const uint4*)(xb + (size_t)EIDX(jj) * 64 + q * 16))
                const uint4* pA = EPTR(jb);
                const uint4* pB = EPTR(jb + 1);
                const uint4* pC = EPTR(jb + 2);
                uint4 A0 = pA[0], A1 = pA[1], A2 = pA[2], A3 = pA[3];
                uint4 B0 = pB[0], B1 = pB[1], B2 = pB[2], B3 = pB[3];
                uint4 C0 = pC[0], C1 = pC[1], C2 = pC[2], C3 = pC[3];
                for (int j = jb; j < je; j += 3) {
                    ACC_QUAD(A0, A1, A2, A3);
                    { const uint4* p = EPTR(j + 3); A0 = p[0]; A1 = p[1]; A2 = p[2]; A3 = p[3]; }
                    if (j + 1 < je) ACC_QUAD(B0, B1, B2, B3);
                    { const uint4* p = EPTR(j + 4); B0 = p[0]; B1 = p[1]; B2 = p[2]; B3 = p[3]; }
                    if (j + 2 < je) ACC_QUAD(C0, C1, C2, C3);
                    { const uint4* p = EPTR(j + 5); C0 = p[0]; C1 = p[1]; C2 = p[2]; C3 = p[3]; }
                }
#undef EIDX
#undef EPTR
            }
        }
        unsigned int pk[16];
#pragma unroll
        for (int j = 0; j < 16; ++j)
            pk[j] = ((unsigned int)f2b(acc[2*j+1]) << 16) | f2b(acc[2*j]);
        uint4* dst = (uint4*)&As[row][q * 32];
        dst[0] = make_uint4(pk[0],  pk[1],  pk[2],  pk[3]);
        dst[1] = make_uint4(pk[4],  pk[5],  pk[6],  pk[7]);
        dst[2] = make_uint4(pk[8],  pk[9],  pk[10], pk[11]);
        dst[3] = make_uint4(pk[12], pk[13], pk[14], pk[15]);
    }
    __syncthreads();

    const int w = t >> 6, l = t & 63, ln = l & 15, quad = l >> 4;
    f32x4 acc2[8];
#pragma unroll
    for (int c = 0; c < 8; ++c) acc2[c] = (f32x4){0.f,0.f,0.f,0.f};
#pragma unroll
    for (int kk = 0; kk < 4; ++kk) {
        int ks = kk * 32 + quad * 8;
        bfrag a = *(const bfrag*)&As[w * 16 + ln][ks];
#pragma unroll
        for (int c = 0; c < 8; ++c) {
            bfrag b = *(const bfrag*)&Ws[c * 16 + ln][ks];
            acc2[c] = __builtin_amdgcn_mfma_f32_16x16x32_bf16(a, b, acc2[c], 0, 0, 0);
        }
    }
    __syncthreads();

#pragma unroll
    for (int c = 0; c < 8; ++c) {
        int col = c * 16 + ln;
        float bias = b1[r * 128 + col];
        float ps = 0.f, pq = 0.f;
#pragma unroll
        for (int reg = 0; reg < 4; ++reg) {
            int lrow = w * 16 + quad * 4 + reg;
            float v = acc2[c][reg] + bias;
            As[lrow][col] = (__bf16)v;
            if (n0 + lrow < Nn) { ps += v; pq += v * v; }
        }
        ps += __shfl_xor(ps, 16); pq += __shfl_xor(pq, 16);
        ps += __shfl_xor(ps, 32); pq += __shfl_xor(pq, 32);
        if (quad == 0) { atomicAdd(&s_sum[col], ps); atomicAdd(&s_sq[col], pq); }
    }
    __syncthreads();

    unsigned short* hr = h + (size_t)r * Nn * 128;
    for (int i = t; i < 2048; i += 512) {
        int m = i >> 4, kc = (i & 15) << 3;
        int gm = n0 + m;
        if (gm < Nn) *(uint4*)(hr + (size_t)gm * 128 + kc) = *(const uint4*)&As[m][kc];
    }
    if (t < 128) {
        atomicAdd(&gsum[r * 128 + t], s_sum[t]);
        atomicAdd(&gsq[r * 128 + t],  s_sq[t]);
    }
}

// ---- BN coefs ----
__global__ void finalize_k(
    const float* __restrict__ gsum, const float* __restrict__ gsq,
    const float* __restrict__ gamma, const float* __restrict__ beta,
    float* __restrict__ coefA, float* __restrict__ coefC)
{
    int i = threadIdx.x;   // 512
    float mean = gsum[i] * (1.0f / Nn);
    float var  = gsq[i] * (1.0f / Nn) - mean * mean;
    float a    = gamma[i] * rsqrtf(fmaxf(var, 0.f) + BN_EPS);
    coefA[i] = a;
    coefC[i] = beta[i] - mean * a;
}

// ---- out = x@W_self + sum_r relu(a*h1+c)@W2_r + biases; 128-row tiles, 512 thr ----
__global__ __launch_bounds__(512) void gemm2f_k(
    const unsigned int* __restrict__ xb,
    const unsigned short* __restrict__ h,
    const unsigned short* __restrict__ WT,
    const float* __restrict__ bself, const float* __restrict__ b2,
    const float* __restrict__ coefA, const float* __restrict__ coefC,
    float* __restrict__ out)
{
    const int n0 = blockIdx.x * 128;
    const int t  = threadIdx.x;
    __shared__ __attribute__((aligned(16))) __bf16 As[128][136];
    __shared__ __attribute__((aligned(16))) __bf16 Ws[128][136];

    const int w = t >> 6, l = t & 63, ln = l & 15, quad = l >> 4;
    f32x4 acc2[8];
#pragma unroll
    for (int c = 0; c < 8; ++c) acc2[c] = (f32x4){0.f,0.f,0.f,0.f};

    for (int rr = 0; rr < 5; ++rr) {
        const unsigned short* Wr = WT + (rr < 4 ? (4 + rr) : 8) * 16384;
        for (int i = t; i < 2048; i += 512) {
            int n = i >> 4, kc = (i & 15) << 3;
            *(uint4*)&Ws[n][kc] = *(const uint4*)(Wr + n * 128 + kc);
        }
        if (rr < 4) {
            const unsigned short* hrp = h + (size_t)rr * Nn * 128;
            const float* cA = coefA + rr * 128;
            const float* cC = coefC + rr * 128;
            for (int i = t; i < 2048; i += 512) {
                int m = i >> 4, kc = (i & 15) << 3;
                int gm = n0 + m;
                uint4 hv = make_uint4(0,0,0,0);
                if (gm < Nn) hv = *(const uint4*)(hrp + (size_t)gm * 128 + kc);
                unsigned int hu[4] = {hv.x, hv.y, hv.z, hv.w};
                unsigned int pk[4];
#pragma unroll
                for (int j = 0; j < 4; ++j) {
                    float v0 = fmaxf(cA[kc + 2*j]     * b2f((unsigned short)(hu[j] & 0xFFFF)) + cC[kc + 2*j],     0.f);
                    float v1 = fmaxf(cA[kc + 2*j + 1] * b2f((unsigned short)(hu[j] >> 16))    + cC[kc + 2*j + 1], 0.f);
                    pk[j] = ((unsigned int)f2b(v1) << 16) | f2b(v0);
                }
                *(uint4*)&As[m][kc] = make_uint4(pk[0], pk[1], pk[2], pk[3]);
            }
        } else {
            for (int i = t; i < 2048; i += 512) {
                int m = i >> 4, kc = (i & 15) << 3;
                int gm = n0 + m;
                uint4 v = make_uint4(0, 0, 0, 0);
                if (gm < Nn) v = *(const uint4*)(xb + (size_t)gm * 64 + (kc >> 1));
                *(uint4*)&As[m][kc] = v;
            }
        }
        __syncthreads();
#pragma unroll
        for (int kk = 0; kk < 4; ++kk) {
            int ks = kk * 32 + quad * 8;
            bfrag a = *(const bfrag*)&As[w * 16 + ln][ks];
#pragma unroll
            for (int c = 0; c < 8; ++c) {
                bfrag b = *(const bfrag*)&Ws[c * 16 + ln][ks];
                acc2[c] = __builtin_amdgcn_mfma_f32_16x16x32_bf16(a, b, acc2[c], 0, 0, 0);
            }
        }
        __syncthreads();
    }

    // Epilogue: fp32 transpose through Ws, coalesced stores; 2 passes of 64 rows
    float bias[8];
#pragma unroll
    for (int c = 0; c < 8; ++c) {
        int col = c * 16 + ln;
        bias[c] = bself[col] + b2[col] + b2[128 + col] + b2[256 + col] + b2[384 + col];
    }
    float* fws = (float*)Ws;
    for (int p = 0; p < 2; ++p) {
        if ((w >> 2) == p) {
#pragma unroll
            for (int c = 0; c < 8; ++c) {
                int lrow = (w & 3) * 16 + quad * 4;
                int col  = c * 16 + ln;
#pragma unroll
                for (int reg = 0; reg < 4; ++reg)
                    fws[(lrow + reg) * 132 + col] = acc2[c][reg] + bias[c];
            }
        }
        __syncthreads();
        for (int i = t; i < 2048; i += 512) {
            int m = i >> 5, kc = (i & 31) << 2;
            int gm = n0 + p * 64 + m;
            if (gm < Nn)
                *(float4*)(out + (size_t)gm * 128 + kc) = *(const float4*)&fws[m * 132 + kc];
        }
        __syncthreads();
    }
}

extern "C" void kernel_launch(void* const* d_in, const int* in_sizes, int n_in,
                              void* d_out, int out_size, void* d_ws, size_t ws_size,
                              hipStream_t stream) {
    const float* x     = (const float*)d_in[0];
    const int*   ei    = (const int*)d_in[1];
    const int*   et    = (const int*)d_in[2];
    const float* Wself = (const float*)d_in[3];
    const float* bself = (const float*)d_in[4];
    const float* W1    = (const float*)d_in[5];
    const float* b1    = (const float*)d_in[6];
    const float* gamma = (const float*)d_in[7];
    const float* beta  = (const float*)d_in[8];
    const float* W2    = (const float*)d_in[9];
    const float* b2    = (const float*)d_in[10];
    float* out = (float*)d_out;

    char* ws = (char*)d_ws;
    int*   scnt  = (int*)(ws + 0);                      // 12512 counters, 64B-strided: 802,816
    float* gsum  = (float*)(ws + 802816);               // 2048
    float* gsq   = (float*)(ws + 804864);               // 2048
    float* coefA = (float*)(ws + 806912);               // 2048
    float* coefC = (float*)(ws + 808960);               // 2048
    int*   ovf   = (int*)(ws + 811008);                 // 4 + 255*8 = 2044
    int*   bkt   = (int*)(ws + 813056);                 // 12512*80*4 = 4,003,840
    unsigned short* h  = (unsigned short*)(ws + 4818688);   // 51,200,000
    unsigned int*   xb = (unsigned int*)(ws + 56018688);    // 12,800,000
    unsigned short* WT = (unsigned short*)(ws + 68818688);  // 294,912

    // zero: scnt + gsum + gsq (+coefA/C harmless) + ovf header/list
    (void)hipMemsetAsync(ws, 0, 813056, stream);

    const int EB = (Ee + 255) / 256;                    // 2344
    prep_k <<<13076, 256, 0, stream>>>(x, W1, W2, Wself, xb, WT);
    fill2_k<<<EB, 256, 0, stream>>>(ei, et, scnt, bkt, ovf);

    dim3 g1((Nn + 127) / 128, Rr);      // (391, 4)
    gemm1f_k<<<g1, 512, 0, stream>>>(xb, scnt, bkt, ovf, WT, b1, h, gsum, gsq);
    finalize_k<<<1, 512, 0, stream>>>(gsum, gsq, gamma, beta, coefA, coefC);
    gemm2f_k<<<(Nn + 127) / 128, 512, 0, stream>>>(
        xb, h, WT, bself, b2, coefA, coefC, out);
}